// Round 7
// baseline (315.885 us; speedup 1.0000x reference)
//
#include <hip/hip_runtime.h>

// LiquidNet (LTC) on MI355X — batch-in-lanes, LDS-free streaming partials.
// prep_k: pack weights into float4 {c, -sg2, w, w*erev} (j-major), build
//         xT[f][b], and transpose state into vT[h][b].
// part_k: lane = batch; wave owns 2 j-columns x one i-slice (LI=48).
//         Per iter: 1 coalesced v load + 2 wave-uniform float4 weight loads,
//         2x (fma, exp2, rcp, 2 fma). No LDS, no syncthreads.
//         1536 step blocks (+768 sensory blocks on first launch) -> ~6 waves/SIMD.
// fin_k:  reduce 16 step + 8 sensory partial slices, leak + divide -> vT.
// 13 launches: prep, 6x (part, fin).

constexpr int B_ = 64;
constexpr int F_ = 256;
constexpr int H_ = 768;
constexpr int UNFOLDS_ = 6;

constexpr int NS_STEP = 16, LI_STEP = 48;   // step: 16 slices x 48 i
constexpr int NS_SENS = 8,  LF_SENS = 32;   // sensory: 8 slices x 32 f
constexpr int JG = H_ / 8;                  // 96 j-groups (8 j per block)
constexpr int STEP_BLOCKS = JG * NS_STEP;   // 1536
constexpr int SENS_BLOCKS = JG * NS_SENS;   // 768
constexpr int FIN_BLOCKS  = (B_ * H_) / 256;     // 192
constexpr int TILE_STEP = (H_ / 32) * (H_ / 32); // 576
constexpr int TILE_SENS = (F_ / 32) * (H_ / 32); // 192
constexpr int PREP_BLOCKS = TILE_STEP + TILE_SENS + 1 + 3;  // +xT, +3 vT-init

// ------------------------------------------------------------------- prep ---
__global__ __launch_bounds__(256) void prep_k(
    const float* __restrict__ sigma, const float* __restrict__ mu,
    const float* __restrict__ W, const float* __restrict__ erev,
    const float* __restrict__ ssig, const float* __restrict__ smu,
    const float* __restrict__ sW, const float* __restrict__ serev,
    const float* __restrict__ inputs, const float* __restrict__ iw,
    const float* __restrict__ ib, const float* __restrict__ state,
    float4* __restrict__ pk_step,   // [H][H] j-major
    float4* __restrict__ pk_sens,   // [H][F] j-major
    float* __restrict__ xT,         // [F][B]
    float* __restrict__ vT_init)    // [H][B]
{
    const int tid = threadIdx.x;
    const float L2E = 1.44269504088896f;
    int blk = blockIdx.x;

    if (blk < TILE_STEP + TILE_SENS) {
        const bool sens = blk >= TILE_STEP;
        if (sens) blk -= TILE_STEP;
        const int ti = blk / 24, tj = blk % 24;     // 24 j-tiles per row
        const int i0 = ti * 32, j0 = tj * 32;
        const float* A0 = sens ? ssig : sigma;
        const float* A1 = sens ? smu : mu;
        const float* A2 = sens ? sW : W;
        const float* A3 = sens ? serev : erev;
        float4* outp = sens ? pk_sens : pk_step;
        const int ILEN = sens ? F_ : H_;

        __shared__ float tsg[32][33], tmu[32][33], tw[32][33], te[32][33];
        const int col = tid & 31;
#pragma unroll
        for (int k = 0; k < 4; ++k) {
            int row = (tid >> 5) + k * 8;
            int idx = (i0 + row) * H_ + j0 + col;
            tsg[row][col] = A0[idx];
            tmu[row][col] = A1[idx];
            tw [row][col] = A2[idx];
            te [row][col] = A3[idx];
        }
        __syncthreads();
#pragma unroll
        for (int k = 0; k < 4; ++k) {
            int jj = (tid >> 5) + k * 8;
            int ii = tid & 31;
            float sg2 = tsg[ii][jj] * L2E;
            float4 v;
            v.x = sg2 * tmu[ii][jj];      // c = sg2*mu
            v.y = -sg2;
            v.z = tw[ii][jj];
            v.w = tw[ii][jj] * te[ii][jj];
            outp[(j0 + jj) * ILEN + (i0 + ii)] = v;
        }
    } else if (blk == TILE_STEP + TILE_SENS) {
        // xT[f][b] = inputs[b][f]*iw[f] + ib[f]
        for (int e = tid; e < B_ * F_; e += 256) {
            int f = e & (F_ - 1), b = e >> 8;
            xT[f * B_ + b] = fmaf(inputs[b * F_ + f], iw[f], ib[f]);
        }
    } else {
        // vT_init[h][b] = state[b][h]; linear coalesced read, scattered write
        const int vb = blk - (TILE_STEP + TILE_SENS + 1);   // 0..2
        for (int e = tid; e < (B_ * H_) / 3; e += 256) {
            int g = vb * ((B_ * H_) / 3) + e;
            int b = g / H_, h = g % H_;
            vT_init[h * B_ + b] = state[g];
        }
    }
}

// --------------------------------------------------------------- partials ---
__global__ __launch_bounds__(256) void part_k(
    const float* __restrict__ vT,        // [H][B]
    const float4* __restrict__ pk_step,
    const float4* __restrict__ pk_sens,
    const float* __restrict__ xT,        // [F][B]
    float* __restrict__ step_part,       // [NS_STEP][2][H][B]
    float* __restrict__ sens_part)       // [NS_SENS][2][H][B]
{
    const int tid  = threadIdx.x;
    const int lane = tid & 63;
    const int wv   = tid >> 6;
    int sb = blockIdx.x;

    if (sb < STEP_BLOCKS) {
        const int jg = sb % JG, sl = sb / JG;
        const int i0 = sl * LI_STEP;
        const int j = jg * 8 + wv * 2;
        const float4* p0 = pk_step + j * H_ + i0;
        const float4* p1 = p0 + H_;
        const float* vp = vT + i0 * B_ + lane;

        float n0 = 0.f, d0 = 0.f, n1 = 0.f, d1 = 0.f;
#pragma unroll 8
        for (int ii = 0; ii < LI_STEP; ++ii) {
            float v  = vp[ii * B_];
            float4 a = p0[ii];
            float4 c = p1[ii];
            float t0 = fmaf(a.y, v, a.x);
            float t1 = fmaf(c.y, v, c.x);
            float s0 = __builtin_amdgcn_rcpf(1.0f + __builtin_amdgcn_exp2f(t0));
            float s1 = __builtin_amdgcn_rcpf(1.0f + __builtin_amdgcn_exp2f(t1));
            d0 = fmaf(a.z, s0, d0);
            n0 = fmaf(a.w, s0, n0);
            d1 = fmaf(c.z, s1, d1);
            n1 = fmaf(c.w, s1, n1);
        }
        float* pn = step_part + (sl * 2 + 0) * H_ * B_;
        float* pd = step_part + (sl * 2 + 1) * H_ * B_;
        pn[j * B_ + lane]       = n0;
        pd[j * B_ + lane]       = d0;
        pn[(j + 1) * B_ + lane] = n1;
        pd[(j + 1) * B_ + lane] = d1;
    } else {
        const int s = sb - STEP_BLOCKS;
        const int jg = s % JG, sl = s / JG;
        const int f0 = sl * LF_SENS;
        const int j = jg * 8 + wv * 2;
        const float4* p0 = pk_sens + j * F_ + f0;
        const float4* p1 = p0 + F_;
        const float* xp = xT + f0 * B_ + lane;

        float n0 = 0.f, d0 = 0.f, n1 = 0.f, d1 = 0.f;
#pragma unroll 8
        for (int ff = 0; ff < LF_SENS; ++ff) {
            float v  = xp[ff * B_];
            float4 a = p0[ff];
            float4 c = p1[ff];
            float t0 = fmaf(a.y, v, a.x);
            float t1 = fmaf(c.y, v, c.x);
            float s0 = __builtin_amdgcn_rcpf(1.0f + __builtin_amdgcn_exp2f(t0));
            float s1 = __builtin_amdgcn_rcpf(1.0f + __builtin_amdgcn_exp2f(t1));
            d0 = fmaf(a.z, s0, d0);
            n0 = fmaf(a.w, s0, n0);
            d1 = fmaf(c.z, s1, d1);
            n1 = fmaf(c.w, s1, n1);
        }
        float* pn = sens_part + (sl * 2 + 0) * H_ * B_;
        float* pd = sens_part + (sl * 2 + 1) * H_ * B_;
        pn[j * B_ + lane]       = n0;
        pd[j * B_ + lane]       = d0;
        pn[(j + 1) * B_ + lane] = n1;
        pd[(j + 1) * B_ + lane] = d1;
    }
}

// --------------------------------------------------------------- finalize ---
__global__ __launch_bounds__(256) void fin_k(
    const float* __restrict__ v_prev,    // [H][B]
    const float* __restrict__ step_part,
    const float* __restrict__ sens_part,
    const float* __restrict__ vleak, const float* __restrict__ gleak,
    const float* __restrict__ cm,
    float* __restrict__ vT_out,          // [H][B]
    float* __restrict__ out0, float* __restrict__ out1, int last)
{
    const int e = blockIdx.x * 256 + threadIdx.x;   // over H*B
    const int b = e & 63, h = e >> 6;
    const int o = h * B_ + b;

    float n = 0.f, d = 0.f;
#pragma unroll
    for (int sl = 0; sl < NS_STEP; ++sl) {
        n += step_part[((sl * 2 + 0) * H_ + h) * B_ + b];
        d += step_part[((sl * 2 + 1) * H_ + h) * B_ + b];
    }
#pragma unroll
    for (int sl = 0; sl < NS_SENS; ++sl) {
        n += sens_part[((sl * 2 + 0) * H_ + h) * B_ + b];
        d += sens_part[((sl * 2 + 1) * H_ + h) * B_ + b];
    }

    float vp = v_prev[o];
    float g  = gleak[h];
    float numer = fmaf(cm[h], vp, fmaf(g, vleak[h], n));
    float denom = cm[h] + g + d;
    float vn = numer / denom;
    vT_out[o] = vn;
    if (last) { out0[b * H_ + h] = vn; out1[b * H_ + h] = vn; }
}

// ----------------------------------------------------------------- launch ---
extern "C" void kernel_launch(void* const* d_in, const int* in_sizes, int n_in,
                              void* d_out, int out_size, void* d_ws, size_t ws_size,
                              hipStream_t stream) {
    const float* inputs = (const float*)d_in[0];
    const float* state  = (const float*)d_in[1];
    const float* iw     = (const float*)d_in[2];
    const float* ib     = (const float*)d_in[3];
    const float* smu    = (const float*)d_in[4];
    const float* ssig   = (const float*)d_in[5];
    const float* sW     = (const float*)d_in[6];
    const float* serev  = (const float*)d_in[7];
    const float* mu     = (const float*)d_in[8];
    const float* sigma  = (const float*)d_in[9];
    const float* W      = (const float*)d_in[10];
    const float* erev   = (const float*)d_in[11];
    const float* vleak  = (const float*)d_in[12];
    const float* gleak  = (const float*)d_in[13];
    const float* cm     = (const float*)d_in[14];
    float* out = (float*)d_out;

    float* ws = (float*)d_ws;
    float4* pk_step = (float4*)ws;                            // H*H float4
    float4* pk_sens = pk_step + H_ * H_;                      // H*F float4
    float*  xT      = (float*)(pk_sens + H_ * F_);            // F*B
    float*  step_part = xT + F_ * B_;                         // NS_STEP*2*H*B
    float*  sens_part = step_part + NS_STEP * 2 * H_ * B_;    // NS_SENS*2*H*B
    float*  vinit     = sens_part + NS_SENS * 2 * H_ * B_;    // H*B
    float*  vb0       = vinit + H_ * B_;                      // H*B
    float*  vb1       = vb0 + H_ * B_;                        // H*B

    prep_k<<<PREP_BLOCKS, 256, 0, stream>>>(
        sigma, mu, W, erev, ssig, smu, sW, serev, inputs, iw, ib, state,
        pk_step, pk_sens, xT, vinit);

    const float* vsrc = vinit;
    for (int t = 0; t < UNFOLDS_; ++t) {
        const int last = (t == UNFOLDS_ - 1);
        float* vdst = (t & 1) ? vb1 : vb0;
        int nblk = (t == 0) ? (STEP_BLOCKS + SENS_BLOCKS) : STEP_BLOCKS;
        part_k<<<nblk, 256, 0, stream>>>(vsrc, pk_step, pk_sens, xT,
                                         step_part, sens_part);
        fin_k<<<FIN_BLOCKS, 256, 0, stream>>>(vsrc, step_part, sens_part,
                                              vleak, gleak, cm, vdst,
                                              out, out + B_ * H_, last);
        vsrc = vdst;
    }
}

// Round 8
// 273.075 us; speedup vs baseline: 1.1568x; 1.1568x over previous
//
#include <hip/hip_runtime.h>

// LiquidNet (LTC) on MI355X — batch-in-lanes, scalar weight loads, LDS v.
// prep_k: pack weights into float4 {c, -sg2, w, w*erev} (j-major), build
//         xT[f][b], transpose state into vT[h][b].
// part_k: lane = batch; wave owns 4 j-columns (8 independent acc chains);
//         j derived via readfirstlane -> weight loads are SGPR-uniform
//         (s_load path); v staged in LDS [i][b], conflict-free reads.
//         768 step blocks (16 slices x 48 j-groups... JG=48, 16 j/block).
// fin_k:  reduce 16 step + 8 sensory partial slices, leak + divide -> vT.
// 13 launches: prep, 6x (part, fin).

constexpr int B_ = 64;
constexpr int F_ = 256;
constexpr int H_ = 768;
constexpr int UNFOLDS_ = 6;

constexpr int JPW = 4;                       // j per wave
constexpr int JPB = 16;                      // j per block (4 waves)
constexpr int JG  = H_ / JPB;                // 48 j-groups
constexpr int NS_STEP = 16, LI_STEP = H_ / NS_STEP;   // 16 x 48
constexpr int NS_SENS = 8,  LF_SENS = F_ / NS_SENS;   // 8 x 32
constexpr int STEP_BLOCKS = JG * NS_STEP;    // 768
constexpr int SENS_BLOCKS = JG * NS_SENS;    // 384
constexpr int FIN_BLOCKS  = (B_ * H_) / 256;      // 192
constexpr int TILE_STEP = (H_ / 32) * (H_ / 32);  // 576
constexpr int TILE_SENS = (F_ / 32) * (H_ / 32);  // 192
constexpr int PREP_BLOCKS = TILE_STEP + TILE_SENS + 1 + 3;

// ------------------------------------------------------------------- prep ---
__global__ __launch_bounds__(256) void prep_k(
    const float* __restrict__ sigma, const float* __restrict__ mu,
    const float* __restrict__ W, const float* __restrict__ erev,
    const float* __restrict__ ssig, const float* __restrict__ smu,
    const float* __restrict__ sW, const float* __restrict__ serev,
    const float* __restrict__ inputs, const float* __restrict__ iw,
    const float* __restrict__ ib, const float* __restrict__ state,
    float4* __restrict__ pk_step,   // [H][H] j-major
    float4* __restrict__ pk_sens,   // [H][F] j-major
    float* __restrict__ xT,         // [F][B]
    float* __restrict__ vT_init)    // [H][B]
{
    const int tid = threadIdx.x;
    const float L2E = 1.44269504088896f;
    int blk = blockIdx.x;

    if (blk < TILE_STEP + TILE_SENS) {
        const bool sens = blk >= TILE_STEP;
        if (sens) blk -= TILE_STEP;
        const int ti = blk / 24, tj = blk % 24;     // 24 j-tiles per row
        const int i0 = ti * 32, j0 = tj * 32;
        const float* A0 = sens ? ssig : sigma;
        const float* A1 = sens ? smu : mu;
        const float* A2 = sens ? sW : W;
        const float* A3 = sens ? serev : erev;
        float4* outp = sens ? pk_sens : pk_step;
        const int ILEN = sens ? F_ : H_;

        __shared__ float tsg[32][33], tmu[32][33], tw[32][33], te[32][33];
        const int col = tid & 31;
#pragma unroll
        for (int k = 0; k < 4; ++k) {
            int row = (tid >> 5) + k * 8;
            int idx = (i0 + row) * H_ + j0 + col;
            tsg[row][col] = A0[idx];
            tmu[row][col] = A1[idx];
            tw [row][col] = A2[idx];
            te [row][col] = A3[idx];
        }
        __syncthreads();
#pragma unroll
        for (int k = 0; k < 4; ++k) {
            int jj = (tid >> 5) + k * 8;
            int ii = tid & 31;
            float sg2 = tsg[ii][jj] * L2E;
            float4 v;
            v.x = sg2 * tmu[ii][jj];      // c = sg2*mu
            v.y = -sg2;
            v.z = tw[ii][jj];
            v.w = tw[ii][jj] * te[ii][jj];
            outp[(j0 + jj) * ILEN + (i0 + ii)] = v;
        }
    } else if (blk == TILE_STEP + TILE_SENS) {
        for (int e = tid; e < B_ * F_; e += 256) {
            int f = e & (F_ - 1), b = e >> 8;
            xT[f * B_ + b] = fmaf(inputs[b * F_ + f], iw[f], ib[f]);
        }
    } else {
        const int vb = blk - (TILE_STEP + TILE_SENS + 1);   // 0..2
        for (int e = tid; e < (B_ * H_) / 3; e += 256) {
            int g = vb * ((B_ * H_) / 3) + e;
            int b = g / H_, h = g % H_;
            vT_init[h * B_ + b] = state[g];
        }
    }
}

// --------------------------------------------------------------- partials ---
__global__ __launch_bounds__(256) void part_k(
    const float* __restrict__ vT,        // [H][B]
    const float4* __restrict__ pk_step,
    const float4* __restrict__ pk_sens,
    const float* __restrict__ xT,        // [F][B]
    float* __restrict__ step_part,       // [NS_STEP][2][H][B]
    float* __restrict__ sens_part)       // [NS_SENS][2][H][B]
{
    const int tid  = threadIdx.x;
    const int lane = tid & 63;
    const int wv   = __builtin_amdgcn_readfirstlane(tid >> 6);
    __shared__ float vs[LI_STEP * B_];   // 12.3 KB (sensory uses 8.2 KB)

    int sb = blockIdx.x;
    if (sb < STEP_BLOCKS) {
        const int jg = sb % JG, sl = sb / JG;
        const int i0 = sl * LI_STEP;

        for (int e = tid; e < LI_STEP * B_; e += 256)
            vs[e] = vT[i0 * B_ + e];     // vT contiguous: [i0..i0+LI)x[B]
        __syncthreads();

        const int j = jg * JPB + wv * JPW;
        const float4* p0 = pk_step + j * H_ + i0;
        const float4* p1 = p0 + H_;
        const float4* p2 = p1 + H_;
        const float4* p3 = p2 + H_;

        float n0 = 0.f, d0 = 0.f, n1 = 0.f, d1 = 0.f;
        float n2 = 0.f, d2 = 0.f, n3 = 0.f, d3 = 0.f;
#pragma unroll 4
        for (int ii = 0; ii < LI_STEP; ++ii) {
            float v  = vs[ii * B_ + lane];
            float4 a = p0[ii], b = p1[ii], c = p2[ii], d = p3[ii];
            float t0 = fmaf(a.y, v, a.x);
            float t1 = fmaf(b.y, v, b.x);
            float t2 = fmaf(c.y, v, c.x);
            float t3 = fmaf(d.y, v, d.x);
            float s0 = __builtin_amdgcn_rcpf(1.0f + __builtin_amdgcn_exp2f(t0));
            float s1 = __builtin_amdgcn_rcpf(1.0f + __builtin_amdgcn_exp2f(t1));
            float s2 = __builtin_amdgcn_rcpf(1.0f + __builtin_amdgcn_exp2f(t2));
            float s3 = __builtin_amdgcn_rcpf(1.0f + __builtin_amdgcn_exp2f(t3));
            d0 = fmaf(a.z, s0, d0);  n0 = fmaf(a.w, s0, n0);
            d1 = fmaf(b.z, s1, d1);  n1 = fmaf(b.w, s1, n1);
            d2 = fmaf(c.z, s2, d2);  n2 = fmaf(c.w, s2, n2);
            d3 = fmaf(d.z, s3, d3);  n3 = fmaf(d.w, s3, n3);
        }
        float* pn = step_part + (sl * 2 + 0) * H_ * B_;
        float* pd = step_part + (sl * 2 + 1) * H_ * B_;
        pn[(j + 0) * B_ + lane] = n0;  pd[(j + 0) * B_ + lane] = d0;
        pn[(j + 1) * B_ + lane] = n1;  pd[(j + 1) * B_ + lane] = d1;
        pn[(j + 2) * B_ + lane] = n2;  pd[(j + 2) * B_ + lane] = d2;
        pn[(j + 3) * B_ + lane] = n3;  pd[(j + 3) * B_ + lane] = d3;
    } else {
        const int s = sb - STEP_BLOCKS;
        const int jg = s % JG, sl = s / JG;
        const int f0 = sl * LF_SENS;

        for (int e = tid; e < LF_SENS * B_; e += 256)
            vs[e] = xT[f0 * B_ + e];
        __syncthreads();

        const int j = jg * JPB + wv * JPW;
        const float4* p0 = pk_sens + j * F_ + f0;
        const float4* p1 = p0 + F_;
        const float4* p2 = p1 + F_;
        const float4* p3 = p2 + F_;

        float n0 = 0.f, d0 = 0.f, n1 = 0.f, d1 = 0.f;
        float n2 = 0.f, d2 = 0.f, n3 = 0.f, d3 = 0.f;
#pragma unroll 4
        for (int ff = 0; ff < LF_SENS; ++ff) {
            float v  = vs[ff * B_ + lane];
            float4 a = p0[ff], b = p1[ff], c = p2[ff], d = p3[ff];
            float t0 = fmaf(a.y, v, a.x);
            float t1 = fmaf(b.y, v, b.x);
            float t2 = fmaf(c.y, v, c.x);
            float t3 = fmaf(d.y, v, d.x);
            float s0 = __builtin_amdgcn_rcpf(1.0f + __builtin_amdgcn_exp2f(t0));
            float s1 = __builtin_amdgcn_rcpf(1.0f + __builtin_amdgcn_exp2f(t1));
            float s2 = __builtin_amdgcn_rcpf(1.0f + __builtin_amdgcn_exp2f(t2));
            float s3 = __builtin_amdgcn_rcpf(1.0f + __builtin_amdgcn_exp2f(t3));
            d0 = fmaf(a.z, s0, d0);  n0 = fmaf(a.w, s0, n0);
            d1 = fmaf(b.z, s1, d1);  n1 = fmaf(b.w, s1, n1);
            d2 = fmaf(c.z, s2, d2);  n2 = fmaf(c.w, s2, n2);
            d3 = fmaf(d.z, s3, d3);  n3 = fmaf(d.w, s3, n3);
        }
        float* pn = sens_part + (sl * 2 + 0) * H_ * B_;
        float* pd = sens_part + (sl * 2 + 1) * H_ * B_;
        pn[(j + 0) * B_ + lane] = n0;  pd[(j + 0) * B_ + lane] = d0;
        pn[(j + 1) * B_ + lane] = n1;  pd[(j + 1) * B_ + lane] = d1;
        pn[(j + 2) * B_ + lane] = n2;  pd[(j + 2) * B_ + lane] = d2;
        pn[(j + 3) * B_ + lane] = n3;  pd[(j + 3) * B_ + lane] = d3;
    }
}

// --------------------------------------------------------------- finalize ---
__global__ __launch_bounds__(256) void fin_k(
    const float* __restrict__ v_prev,    // [H][B]
    const float* __restrict__ step_part,
    const float* __restrict__ sens_part,
    const float* __restrict__ vleak, const float* __restrict__ gleak,
    const float* __restrict__ cm,
    float* __restrict__ vT_out,          // [H][B]
    float* __restrict__ out0, float* __restrict__ out1, int last)
{
    const int e = blockIdx.x * 256 + threadIdx.x;   // over H*B
    const int b = e & 63, h = e >> 6;
    const int o = h * B_ + b;

    float n = 0.f, d = 0.f;
#pragma unroll
    for (int sl = 0; sl < NS_STEP; ++sl) {
        n += step_part[((sl * 2 + 0) * H_ + h) * B_ + b];
        d += step_part[((sl * 2 + 1) * H_ + h) * B_ + b];
    }
#pragma unroll
    for (int sl = 0; sl < NS_SENS; ++sl) {
        n += sens_part[((sl * 2 + 0) * H_ + h) * B_ + b];
        d += sens_part[((sl * 2 + 1) * H_ + h) * B_ + b];
    }

    float vp = v_prev[o];
    float g  = gleak[h];
    float numer = fmaf(cm[h], vp, fmaf(g, vleak[h], n));
    float denom = cm[h] + g + d;
    float vn = numer / denom;
    vT_out[o] = vn;
    if (last) { out0[b * H_ + h] = vn; out1[b * H_ + h] = vn; }
}

// ----------------------------------------------------------------- launch ---
extern "C" void kernel_launch(void* const* d_in, const int* in_sizes, int n_in,
                              void* d_out, int out_size, void* d_ws, size_t ws_size,
                              hipStream_t stream) {
    const float* inputs = (const float*)d_in[0];
    const float* state  = (const float*)d_in[1];
    const float* iw     = (const float*)d_in[2];
    const float* ib     = (const float*)d_in[3];
    const float* smu    = (const float*)d_in[4];
    const float* ssig   = (const float*)d_in[5];
    const float* sW     = (const float*)d_in[6];
    const float* serev  = (const float*)d_in[7];
    const float* mu     = (const float*)d_in[8];
    const float* sigma  = (const float*)d_in[9];
    const float* W      = (const float*)d_in[10];
    const float* erev   = (const float*)d_in[11];
    const float* vleak  = (const float*)d_in[12];
    const float* gleak  = (const float*)d_in[13];
    const float* cm     = (const float*)d_in[14];
    float* out = (float*)d_out;

    float* ws = (float*)d_ws;
    float4* pk_step = (float4*)ws;                            // H*H float4
    float4* pk_sens = pk_step + H_ * H_;                      // H*F float4
    float*  xT      = (float*)(pk_sens + H_ * F_);            // F*B
    float*  step_part = xT + F_ * B_;                         // NS_STEP*2*H*B
    float*  sens_part = step_part + NS_STEP * 2 * H_ * B_;    // NS_SENS*2*H*B
    float*  vinit     = sens_part + NS_SENS * 2 * H_ * B_;    // H*B
    float*  vb0       = vinit + H_ * B_;                      // H*B
    float*  vb1       = vb0 + H_ * B_;                        // H*B

    prep_k<<<PREP_BLOCKS, 256, 0, stream>>>(
        sigma, mu, W, erev, ssig, smu, sW, serev, inputs, iw, ib, state,
        pk_step, pk_sens, xT, vinit);

    const float* vsrc = vinit;
    for (int t = 0; t < UNFOLDS_; ++t) {
        const int last = (t == UNFOLDS_ - 1);
        float* vdst = (t & 1) ? vb1 : vb0;
        int nblk = (t == 0) ? (STEP_BLOCKS + SENS_BLOCKS) : STEP_BLOCKS;
        part_k<<<nblk, 256, 0, stream>>>(vsrc, pk_step, pk_sens, xT,
                                         step_part, sens_part);
        fin_k<<<FIN_BLOCKS, 256, 0, stream>>>(vsrc, step_part, sens_part,
                                              vleak, gleak, cm, vdst,
                                              out, out + B_ * H_, last);
        vsrc = vdst;
    }
}

// Round 9
// 210.234 us; speedup vs baseline: 1.5025x; 1.2989x over previous
//
#include <hip/hip_runtime.h>

// LiquidNet (LTC) on MI355X — all-LDS inner loop.
// Lesson R6/R7/R8: mixing s_load weights (out-of-order, lgkmcnt) or vector
// weight loads (in-order vmcnt) with the per-iter v read exposes full L2
// latency every unroll group. Fix: stage BOTH v-chunk and weight tile into
// LDS once per block; inner loop = pure ds_read (in-order -> counted lgkmcnt).
// part_k: lane = batch; 4 waves x 2 j; LI=64 i-chunk; LDS 24KB/block.
// 13 launches: prep, 6x (part, fin).

constexpr int B_ = 64;
constexpr int F_ = 256;
constexpr int H_ = 768;
constexpr int UNFOLDS_ = 6;

constexpr int LI  = 64;                     // i (or f) chunk per block
constexpr int JPB = 8;                      // j per block (4 waves x 2)
constexpr int JG  = H_ / JPB;               // 96 j-groups
constexpr int NS_STEP = H_ / LI;            // 12 slices
constexpr int NS_SENS = F_ / LI;            // 4 slices
constexpr int STEP_BLOCKS = JG * NS_STEP;   // 1152
constexpr int SENS_BLOCKS = JG * NS_SENS;   // 384
constexpr int FIN_BLOCKS  = (B_ * H_) / 256;      // 192
constexpr int TILE_STEP = (H_ / 32) * (H_ / 32);  // 576
constexpr int TILE_SENS = (F_ / 32) * (H_ / 32);  // 192
constexpr int PREP_BLOCKS = TILE_STEP + TILE_SENS + 1 + 3;

// ------------------------------------------------------------------- prep ---
__global__ __launch_bounds__(256) void prep_k(
    const float* __restrict__ sigma, const float* __restrict__ mu,
    const float* __restrict__ W, const float* __restrict__ erev,
    const float* __restrict__ ssig, const float* __restrict__ smu,
    const float* __restrict__ sW, const float* __restrict__ serev,
    const float* __restrict__ inputs, const float* __restrict__ iw,
    const float* __restrict__ ib, const float* __restrict__ state,
    float4* __restrict__ pk_step,   // [H][H] j-major: {c, -sg2, w, w*erev}
    float4* __restrict__ pk_sens,   // [H][F] j-major
    float* __restrict__ xT,         // [F][B]
    float* __restrict__ vT_init)    // [H][B]
{
    const int tid = threadIdx.x;
    const float L2E = 1.44269504088896f;
    int blk = blockIdx.x;

    if (blk < TILE_STEP + TILE_SENS) {
        const bool sens = blk >= TILE_STEP;
        if (sens) blk -= TILE_STEP;
        const int ti = blk / 24, tj = blk % 24;     // 24 j-tiles per row
        const int i0 = ti * 32, j0 = tj * 32;
        const float* A0 = sens ? ssig : sigma;
        const float* A1 = sens ? smu : mu;
        const float* A2 = sens ? sW : W;
        const float* A3 = sens ? serev : erev;
        float4* outp = sens ? pk_sens : pk_step;
        const int ILEN = sens ? F_ : H_;

        __shared__ float tsg[32][33], tmu[32][33], tw[32][33], te[32][33];
        const int col = tid & 31;
#pragma unroll
        for (int k = 0; k < 4; ++k) {
            int row = (tid >> 5) + k * 8;
            int idx = (i0 + row) * H_ + j0 + col;
            tsg[row][col] = A0[idx];
            tmu[row][col] = A1[idx];
            tw [row][col] = A2[idx];
            te [row][col] = A3[idx];
        }
        __syncthreads();
#pragma unroll
        for (int k = 0; k < 4; ++k) {
            int jj = (tid >> 5) + k * 8;
            int ii = tid & 31;
            float sg2 = tsg[ii][jj] * L2E;
            float4 v;
            v.x = sg2 * tmu[ii][jj];      // c = sg2*mu
            v.y = -sg2;
            v.z = tw[ii][jj];
            v.w = tw[ii][jj] * te[ii][jj];
            outp[(j0 + jj) * ILEN + (i0 + ii)] = v;
        }
    } else if (blk == TILE_STEP + TILE_SENS) {
        for (int e = tid; e < B_ * F_; e += 256) {
            int f = e & (F_ - 1), b = e >> 8;
            xT[f * B_ + b] = fmaf(inputs[b * F_ + f], iw[f], ib[f]);
        }
    } else {
        const int vb = blk - (TILE_STEP + TILE_SENS + 1);   // 0..2
        for (int e = tid; e < (B_ * H_) / 3; e += 256) {
            int g = vb * ((B_ * H_) / 3) + e;
            int b = g / H_, h = g % H_;
            vT_init[h * B_ + b] = state[g];
        }
    }
}

// --------------------------------------------------------------- partials ---
__global__ __launch_bounds__(256) void part_k(
    const float* __restrict__ vT,        // [H][B]
    const float4* __restrict__ pk_step,
    const float4* __restrict__ pk_sens,
    const float* __restrict__ xT,        // [F][B]
    float* __restrict__ step_part,       // [NS_STEP][2][H][B]
    float* __restrict__ sens_part)       // [NS_SENS][2][H][B]
{
    const int tid  = threadIdx.x;
    const int lane = tid & 63;
    const int wv   = __builtin_amdgcn_readfirstlane(tid >> 6);

    __shared__ float4 vs4[LI * B_ / 4];  // 16 KB: v (or x) chunk
    __shared__ float4 lw[JPB * LI];      // 8 KB: weight tile

    int sb = blockIdx.x;
    int jg, sl, ilen;
    const float4* pkb;
    const float* vsrc;
    float* pout;
    if (sb < STEP_BLOCKS) {
        jg = sb % JG; sl = sb / JG; ilen = H_;
        pkb = pk_step; vsrc = vT; pout = step_part;
    } else {
        int s = sb - STEP_BLOCKS;
        jg = s % JG; sl = s / JG; ilen = F_;
        pkb = pk_sens; vsrc = xT; pout = sens_part;
    }
    const int i0 = sl * LI, j0 = jg * JPB;

    // stage v-chunk: contiguous LI*B floats
    const float4* gv = (const float4*)(vsrc + i0 * B_);
    for (int e = tid; e < LI * B_ / 4; e += 256) vs4[e] = gv[e];
    // stage weight tile: JPB rows of LI float4
    for (int e = tid; e < JPB * LI; e += 256) {
        int r = e >> 6, c = e & (LI - 1);
        lw[e] = pkb[(j0 + r) * ilen + i0 + c];
    }
    __syncthreads();

    const float* vs = (const float*)vs4;
    const int jl = wv * 2;
    const float4* w0 = &lw[(jl + 0) * LI];
    const float4* w1 = &lw[(jl + 1) * LI];

    float n0 = 0.f, d0 = 0.f, n1 = 0.f, d1 = 0.f;
#pragma unroll 4
    for (int ii = 0; ii < LI; ++ii) {
        float v  = vs[ii * B_ + lane];
        float4 a = w0[ii], b = w1[ii];
        float t0 = fmaf(a.y, v, a.x);
        float t1 = fmaf(b.y, v, b.x);
        float s0 = __builtin_amdgcn_rcpf(1.0f + __builtin_amdgcn_exp2f(t0));
        float s1 = __builtin_amdgcn_rcpf(1.0f + __builtin_amdgcn_exp2f(t1));
        d0 = fmaf(a.z, s0, d0);  n0 = fmaf(a.w, s0, n0);
        d1 = fmaf(b.z, s1, d1);  n1 = fmaf(b.w, s1, n1);
    }

    const int j = j0 + jl;
    float* pn = pout + (sl * 2 + 0) * (H_ * B_);
    float* pd = pout + (sl * 2 + 1) * (H_ * B_);
    pn[(j + 0) * B_ + lane] = n0;  pd[(j + 0) * B_ + lane] = d0;
    pn[(j + 1) * B_ + lane] = n1;  pd[(j + 1) * B_ + lane] = d1;
}

// --------------------------------------------------------------- finalize ---
__global__ __launch_bounds__(256) void fin_k(
    const float* __restrict__ v_prev,    // [H][B]
    const float* __restrict__ step_part,
    const float* __restrict__ sens_part,
    const float* __restrict__ vleak, const float* __restrict__ gleak,
    const float* __restrict__ cm,
    float* __restrict__ vT_out,          // [H][B]
    float* __restrict__ out0, float* __restrict__ out1, int last)
{
    const int e = blockIdx.x * 256 + threadIdx.x;   // over H*B
    const int b = e & 63, h = e >> 6;
    const int o = h * B_ + b;

    float n = 0.f, d = 0.f;
#pragma unroll
    for (int sl = 0; sl < NS_STEP; ++sl) {
        n += step_part[((sl * 2 + 0) * H_ + h) * B_ + b];
        d += step_part[((sl * 2 + 1) * H_ + h) * B_ + b];
    }
#pragma unroll
    for (int sl = 0; sl < NS_SENS; ++sl) {
        n += sens_part[((sl * 2 + 0) * H_ + h) * B_ + b];
        d += sens_part[((sl * 2 + 1) * H_ + h) * B_ + b];
    }

    float vp = v_prev[o];
    float g  = gleak[h];
    float numer = fmaf(cm[h], vp, fmaf(g, vleak[h], n));
    float denom = cm[h] + g + d;
    float vn = numer / denom;
    vT_out[o] = vn;
    if (last) { out0[b * H_ + h] = vn; out1[b * H_ + h] = vn; }
}

// ----------------------------------------------------------------- launch ---
extern "C" void kernel_launch(void* const* d_in, const int* in_sizes, int n_in,
                              void* d_out, int out_size, void* d_ws, size_t ws_size,
                              hipStream_t stream) {
    const float* inputs = (const float*)d_in[0];
    const float* state  = (const float*)d_in[1];
    const float* iw     = (const float*)d_in[2];
    const float* ib     = (const float*)d_in[3];
    const float* smu    = (const float*)d_in[4];
    const float* ssig   = (const float*)d_in[5];
    const float* sW     = (const float*)d_in[6];
    const float* serev  = (const float*)d_in[7];
    const float* mu     = (const float*)d_in[8];
    const float* sigma  = (const float*)d_in[9];
    const float* W      = (const float*)d_in[10];
    const float* erev   = (const float*)d_in[11];
    const float* vleak  = (const float*)d_in[12];
    const float* gleak  = (const float*)d_in[13];
    const float* cm     = (const float*)d_in[14];
    float* out = (float*)d_out;

    float* ws = (float*)d_ws;
    float4* pk_step = (float4*)ws;                            // H*H float4
    float4* pk_sens = pk_step + H_ * H_;                      // H*F float4
    float*  xT      = (float*)(pk_sens + H_ * F_);            // F*B
    float*  step_part = xT + F_ * B_;                         // NS_STEP*2*H*B
    float*  sens_part = step_part + NS_STEP * 2 * H_ * B_;    // NS_SENS*2*H*B
    float*  vinit     = sens_part + NS_SENS * 2 * H_ * B_;    // H*B
    float*  vb0       = vinit + H_ * B_;                      // H*B
    float*  vb1       = vb0 + H_ * B_;                        // H*B

    prep_k<<<PREP_BLOCKS, 256, 0, stream>>>(
        sigma, mu, W, erev, ssig, smu, sW, serev, inputs, iw, ib, state,
        pk_step, pk_sens, xT, vinit);

    const float* vsrc = vinit;
    for (int t = 0; t < UNFOLDS_; ++t) {
        const int last = (t == UNFOLDS_ - 1);
        float* vdst = (t & 1) ? vb1 : vb0;
        int nblk = (t == 0) ? (STEP_BLOCKS + SENS_BLOCKS) : STEP_BLOCKS;
        part_k<<<nblk, 256, 0, stream>>>(vsrc, pk_step, pk_sens, xT,
                                         step_part, sens_part);
        fin_k<<<FIN_BLOCKS, 256, 0, stream>>>(vsrc, step_part, sens_part,
                                              vleak, gleak, cm, vdst,
                                              out, out + B_ * H_, last);
        vsrc = vdst;
    }
}